// Round 20
// baseline (1032.949 us; speedup 1.0000x reference)
//
#include <hip/hip_runtime.h>

// ---------------------------------------------------------------------------
// FusedSparseLMHead: weighted-mean CE over h @ W^T without materializing logits.
//   h: [4096, 2048] f32, W: [65536, 2048] f32, labels: [4096] int, w: [4096] f32
// Round 20: r15 base (best: 660 us gemm) with mfma_i32_32x32x32_i8 -- HALF the
//   instruction count (32/wave/K-tile vs 64), each instr 2x longer (36.6 cyc)
//   -> frees issue slots for VALU + 24 ds_reads under the MFMA shadow.
//   Geometry: 256^2 tile, BK=128 i8, 8 waves; wave tile 128x64 = 4 m-frags x
//   2 n-frags of 32x32. Staging/ring/numerics = r15 verbatim (4-sweep
//   c^(r&7) swizzle, 2-phase/3-barrier, A(t+1) ph0 / B(t+2) ph1, boundary
//   vmcnt(4) counted -- queue proof unchanged).
//   Read addressing (32x32): row = base + (l&31) (bases mult of 32 ->
//   r&7 == l&7 ... r&7 = (l&31)&7 = l&7); k-step ks reads G-chunks ks*2+(l>>5)
//   stored at chunk ^ (l&7). Bank check: c = (ks*2+(l>>5))^(l&7) -- for each
//   ks, c covers each residue exactly 8x across 64 lanes, granules distinct
//   (l vs l+32 flip l>>5 -> different c) => minimal bank load.
//   A frag k-map: row = l&31, k = (l>>5)*16 + j (verified family, r5/r15).
//   C/D 32x32 (r5-verified): col = l&31, row = (rg&3) + 8*(rg>>2) + 4*(l>>5).
// ---------------------------------------------------------------------------

typedef __attribute__((ext_vector_type(4)))   float f32x4;
typedef __attribute__((ext_vector_type(8)))   float f32x8;
typedef __attribute__((ext_vector_type(4)))   int   i32x4;
typedef __attribute__((ext_vector_type(16)))  int   i32x16;

#define N_TOK 4096
#define DIM   2048          // i8 bytes per row
#define VOCAB 65536
#define BM    256
#define BN    256
#define BK    128           // i8 elements per K-tile
#define NT    (DIM / BK)    // 16 K-tiles
#define NCH   (VOCAB / BN)  // 256 vocab chunks
#define NTB   (N_TOK / BM)  // 16 token blocks

__device__ __forceinline__ void gload_lds16(const void* g, void* l) {
    __builtin_amdgcn_global_load_lds(
        (const __attribute__((address_space(1))) void*)g,
        (__attribute__((address_space(3))) void*)l, 16, 0, 0);
}

__device__ __forceinline__ void bar() {
    asm volatile("" ::: "memory");
    __builtin_amdgcn_s_barrier();
    asm volatile("" ::: "memory");
}

// ------------------------------------------------- convert f32 -> int8 -----
__global__ __launch_bounds__(256) void convert_f32_i8(
    const float* __restrict__ src, signed char* __restrict__ dst,
    long n, float scale)
{
    long i = ((long)blockIdx.x * 256 + threadIdx.x) * 8;
    if (i + 8 > n) return;
    f32x8 v = *(const f32x8*)(src + i);
    signed char o[8];
    #pragma unroll
    for (int j = 0; j < 8; ++j) {
        float x = v[j] * scale;
        x = fminf(fmaxf(x, -127.0f), 127.0f);
        o[j] = (signed char)__float2int_rn(x);
    }
    *(uint2*)(dst + i) = *(const uint2*)o;   // plain contiguous, coalesced
}

// ---------- i8 32x32x32, 256^2 tile, 2-phase/3-barrier GEMM+LSE ------------
__global__ __launch_bounds__(512, 2) void gemm_lse(
    const signed char* __restrict__ h8,      // [4096][2048] i8 (x16)
    const signed char* __restrict__ W8,      // [seg_rows][2048] i8 (x1024)
    float* __restrict__ part_m, float* __restrict__ part_s, int chunk0)
{
    __shared__ unsigned char A_lds[2][32768];   // [par][256r x 128B] 64 KB
    __shared__ unsigned char B_lds[2][32768];   // 64 KB

    const int tid  = threadIdx.x;
    const int lane = tid & 63;
    const int w    = tid >> 6;       // wave 0..7
    const int wm   = w >> 2;         // 0..1 : token half (128 rows)
    const int wn   = w & 3;          // 0..3 : vocab quarter (64 cols)

    // bijective XCD-aware remap, token-fastest decode
    const int nwg  = gridDim.x;
    const int orig = blockIdx.x;
    const int q8 = nwg >> 3, r8 = nwg & 7;
    const int xcd = orig & 7;
    const int wg  = (xcd < r8 ? xcd * (q8 + 1) : r8 * (q8 + 1) + (xcd - r8) * q8)
                    + (orig >> 3);
    const int tok_blk = wg & (NTB - 1);
    const int voc_blk = wg >> 4;                 // NTB == 16

    const long arow0 = (long)tok_blk * BM;
    const signed char* Ab = h8 + arow0 * DIM;
    const signed char* Bb = W8 + (long)voc_blk * BN * DIM;

    i32x16 acc[4][2];
    #pragma unroll
    for (int i = 0; i < 4; ++i)
        #pragma unroll
        for (int j = 0; j < 2; ++j)
            #pragma unroll
            for (int e = 0; e < 16; ++e)
                acc[i][j][e] = 0;

    // ---- staging (r15 verbatim): tile = 256r x 8 chunks(16B); 4 sweeps.
    // Sweep j rows [j*64, j*64+64): r = j*64 + (tid>>3), c = tid&7;
    // src chunk c^(r&7) -> LDS[r][c] = G[r][c^(r&7)] (linear dest).
    const long soff = (long)(tid >> 3) * DIM + ((tid & 7) ^ ((tid >> 3) & 7)) * 16;
    const int  sdb  = w * 1024;     // wave-uniform dest base (bytes)

#define SW_A(t, j, PD)                                                        \
    gload_lds16(Ab + (t) * BK + soff + (long)(j) * 64 * DIM,                  \
                (char*)&A_lds[PD][0] + sdb + (j) * 8192);
#define SW_B(t, j, PD)                                                        \
    gload_lds16(Bb + (t) * BK + soff + (long)(j) * 64 * DIM,                  \
                (char*)&B_lds[PD][0] + sdb + (j) * 8192);

    // ---- fragment read constants: row byte = (l&31)*128; k-step ks chunk
    // read at ((ks*2 + (l>>5)) ^ (l&7)) * 16 (balanced, distinct -- header).
    const int lrow = (lane & 31) * 128;
    int cx[4];
    #pragma unroll
    for (int ks = 0; ks < 4; ++ks)
        cx[ks] = (((ks * 2) + (lane >> 5)) ^ (lane & 7)) * 16;

    // one ds_read_b128 = one 32x32x32 operand (16 contiguous-k i8 per lane)
#define LDA1(MF, KS, AH) (*(const i32x4*)((AH) + (MF) * 4096 + lrow + cx[KS]))
#define LDB1(NF, KS, BH) (*(const i32x4*)((BH) + (NF) * 4096 + lrow + cx[KS]))

#define MFMA16(KS0)                                                           \
    __builtin_amdgcn_s_setprio(1);                                            \
    _Pragma("unroll")                                                         \
    for (int ks = 0; ks < 2; ++ks)                                            \
        _Pragma("unroll")                                                     \
        for (int mf = 0; mf < 4; ++mf)                                        \
            _Pragma("unroll")                                                 \
            for (int nf = 0; nf < 2; ++nf)                                    \
                acc[mf][nf] = __builtin_amdgcn_mfma_i32_32x32x32_i8(          \
                    aR[mf][ks], bR[nf][ks], acc[mf][nf], 0, 0, 0);            \
    __builtin_amdgcn_s_setprio(0);

#define WAITL()                                                               \
    asm volatile("s_waitcnt lgkmcnt(0)" ::: "memory");                        \
    __builtin_amdgcn_sched_barrier(0);

// One K-tile(128): 2 phases, 3 barriers (r14/r15 structure, proofs carry).
// ph0: reads ks0-1 (8 A + 4 B b128) | stage A(t+1) | bar | lgkm0 | 16 MFMA
// ph1: reads ks2-3 | bar | stage B(t+2) | lgkm0 | 16 MFMA | vmcnt(4) | bar
#define KTILE(P, t)                                                           \
    {                                                                         \
        const char* Ah = (const char*)&A_lds[P][0] + wm * 16384;              \
        const char* Bh = (const char*)&B_lds[P][0] + wn * 8192;               \
        i32x4 aR[4][2], bR[2][2];                                             \
        _Pragma("unroll")                                                     \
        for (int mf = 0; mf < 4; ++mf) {                                      \
            aR[mf][0] = LDA1(mf, 0, Ah);                                      \
            aR[mf][1] = LDA1(mf, 1, Ah);                                      \
        }                                                                     \
        _Pragma("unroll")                                                     \
        for (int nf = 0; nf < 2; ++nf) {                                      \
            bR[nf][0] = LDB1(nf, 0, Bh);                                      \
            bR[nf][1] = LDB1(nf, 1, Bh);                                      \
        }                                                                     \
        if ((t) + 1 < NT) {                                                   \
            SW_A((t) + 1, 0, (P) ^ 1) SW_A((t) + 1, 1, (P) ^ 1)               \
            SW_A((t) + 1, 2, (P) ^ 1) SW_A((t) + 1, 3, (P) ^ 1)               \
        }                                                                     \
        bar(); WAITL()                                                        \
        MFMA16(0)                                                             \
        _Pragma("unroll")                                                     \
        for (int mf = 0; mf < 4; ++mf) {                                      \
            aR[mf][0] = LDA1(mf, 2, Ah);                                      \
            aR[mf][1] = LDA1(mf, 3, Ah);                                      \
        }                                                                     \
        _Pragma("unroll")                                                     \
        for (int nf = 0; nf < 2; ++nf) {                                      \
            bR[nf][0] = LDB1(nf, 2, Bh);                                      \
            bR[nf][1] = LDB1(nf, 3, Bh);                                      \
        }                                                                     \
        bar();                                                                \
        if ((t) + 2 < NT) {                                                   \
            SW_B((t) + 2, 0, P) SW_B((t) + 2, 1, P)                           \
            SW_B((t) + 2, 2, P) SW_B((t) + 2, 3, P)                           \
        }                                                                     \
        WAITL()                                                               \
        MFMA16(2)                                                             \
        if ((t) < NT - 2) { asm volatile("s_waitcnt vmcnt(4)" ::: "memory"); }\
        else              { asm volatile("s_waitcnt vmcnt(0)" ::: "memory"); }\
        bar();                                                                \
    }

    // prologue: A(0)->A[0], B(0)->B[0], B(1)->B[1]; vmcnt(4): A(0),B(0)
    // landed, B(1) floats (drained by boundary(0)'s vmcnt(4) before t=1).
    SW_A(0, 0, 0) SW_A(0, 1, 0) SW_A(0, 2, 0) SW_A(0, 3, 0)
    SW_B(0, 0, 0) SW_B(0, 1, 0) SW_B(0, 2, 0) SW_B(0, 3, 0)
    SW_B(1, 0, 1) SW_B(1, 1, 1) SW_B(1, 2, 1) SW_B(1, 3, 1)
    asm volatile("s_waitcnt vmcnt(4)" ::: "memory");
    bar();

    for (int t = 0; t < NT; t += 2) {
        KTILE(0, t)
        KTILE(1, t + 1)
    }
#undef KTILE
#undef SW_A
#undef SW_B
#undef LDA1
#undef LDB1
#undef MFMA16
#undef WAITL

    // ---- epilogue: exact dequant (1/16384), per-token (max, sumexp) -------
    // 32x32 C/D (r5-verified): col = wn*64 + nf*32 + (l&31);
    // row = wm*128 + mf*32 + (rg&3) + 8*(rg>>2) + 4*(l>>5). 32-wide shfl.
    const float INV = 1.0f / 16384.0f;
    float* red_m = (float*)&A_lds[0][0];          // 4 KB
    float* red_s = ((float*)&A_lds[0][0]) + 1024; // 4 KB
    #pragma unroll
    for (int mf = 0; mf < 4; ++mf) {
        #pragma unroll
        for (int rg = 0; rg < 16; ++rg) {
            float v0 = (float)acc[mf][0][rg] * INV;
            float v1 = (float)acc[mf][1][rg] * INV;
            float mx = fmaxf(v0, v1);
            #pragma unroll
            for (int msk = 1; msk < 32; msk <<= 1)
                mx = fmaxf(mx, __shfl_xor(mx, msk, 64));
            float se = __expf(v0 - mx) + __expf(v1 - mx);
            #pragma unroll
            for (int msk = 1; msk < 32; msk <<= 1)
                se += __shfl_xor(se, msk, 64);
            if ((lane & 31) == 0) {
                const int row = wm * 128 + mf * 32 + (rg & 3) + 8 * (rg >> 2) +
                                4 * (lane >> 5);
                red_m[row * 4 + wn] = mx;
                red_s[row * 4 + wn] = se;
            }
        }
    }
    __syncthreads();
    if (tid < 256) {
        float M = red_m[tid * 4], S = red_s[tid * 4];
        #pragma unroll
        for (int j = 1; j < 4; ++j) {
            const float m2 = red_m[tid * 4 + j], s2 = red_s[tid * 4 + j];
            const float Mn = fmaxf(M, m2);
            S = S * __expf(M - Mn) + s2 * __expf(m2 - Mn);
            M = Mn;
        }
        part_m[(arow0 + tid) * NCH + chunk0 + voc_blk] = M;
        part_s[(arow0 + tid) * NCH + chunk0 + voc_blk] = S;
    }
}

// ------------------------------------------------------- exact label dot ----
__global__ __launch_bounds__(256) void label_dot(
    const float* __restrict__ h, const float* __restrict__ W,
    const void* __restrict__ labels, float* __restrict__ lab_logit)
{
    bool is64 = true;
    #pragma unroll
    for (int i = 0; i < 8; ++i) {
        long long v = ((const long long*)labels)[i];
        if (v < 0 || v >= VOCAB) is64 = false;
    }
    const int t = blockIdx.x;
    const int lab = is64 ? (int)((const long long*)labels)[t]
                         : ((const int*)labels)[t];
    const float4* hp = (const float4*)(h + (long)t * DIM);
    const float4* wp = (const float4*)(W + (long)lab * DIM);
    float s = 0.f;
    #pragma unroll
    for (int j = 0; j < 2; ++j) {
        const float4 a = hp[threadIdx.x + j * 256];
        const float4 b = wp[threadIdx.x + j * 256];
        s += a.x * b.x + a.y * b.y + a.z * b.z + a.w * b.w;
    }
    #pragma unroll
    for (int msk = 1; msk < 64; msk <<= 1) s += __shfl_xor(s, msk, 64);
    __shared__ float ps[4];
    if ((threadIdx.x & 63) == 0) ps[threadIdx.x >> 6] = s;
    __syncthreads();
    if (threadIdx.x == 0) lab_logit[t] = ps[0] + ps[1] + ps[2] + ps[3];
}

// ---------------------------------------------------- per-token LSE merge ---
__global__ __launch_bounds__(256) void finalize_nll(
    const float* __restrict__ part_m, const float* __restrict__ part_s,
    const float* __restrict__ lab_logit, const float* __restrict__ wts,
    float* __restrict__ wnll)
{
    const int t    = blockIdx.x * 4 + (threadIdx.x >> 6);  // one wave / token
    const int lane = threadIdx.x & 63;
    float m = -3.4e38f, s = 0.f;
    #pragma unroll
    for (int j = 0; j < 4; ++j) {
        const int c = j * 64 + lane;
        const float pm = part_m[(long)t * NCH + c];
        const float ps = part_s[(long)t * NCH + c];
        const float M = fmaxf(m, pm);
        s = s * __expf(m - M) + ps * __expf(pm - M);
        m = M;
    }
    #pragma unroll
    for (int msk = 1; msk < 64; msk <<= 1) {
        const float om = __shfl_xor(m, msk, 64);
        const float os = __shfl_xor(s, msk, 64);
        const float M = fmaxf(m, om);
        s = s * __expf(m - M) + os * __expf(om - M);
        m = M;
    }
    if (lane == 0) {
        const float lse = m + logf(s);
        wnll[t] = wts[t] * (lse - lab_logit[t]);
    }
}

// -------------------------------------------------- deterministic reduce ----
__global__ __launch_bounds__(1024) void final_reduce(
    const float* __restrict__ wnll, const float* __restrict__ wts,
    float* __restrict__ out)
{
    float a = 0.f, b = 0.f;
    #pragma unroll
    for (int j = 0; j < 4; ++j) {
        const int i = threadIdx.x + j * 1024;
        a += wnll[i];
        b += wts[i];
    }
    #pragma unroll
    for (int msk = 1; msk < 64; msk <<= 1) {
        a += __shfl_xor(a, msk, 64);
        b += __shfl_xor(b, msk, 64);
    }
    __shared__ float pa[16], pb[16];
    if ((threadIdx.x & 63) == 0) {
        pa[threadIdx.x >> 6] = a;
        pb[threadIdx.x >> 6] = b;
    }
    __syncthreads();
    if (threadIdx.x == 0) {
        float A = 0.f, B = 0.f;
        #pragma unroll
        for (int i = 0; i < 16; ++i) { A += pa[i]; B += pb[i]; }
        out[0] = A / B;
    }
}

// ----------------------------------------------------------------- launch ---
extern "C" void kernel_launch(void* const* d_in, const int* in_sizes, int n_in,
                              void* d_out, int out_size, void* d_ws, size_t ws_size,
                              hipStream_t stream)
{
    const float* h      = (const float*)d_in[0];
    const void*  labels = d_in[1];
    const float* wts    = (const float*)d_in[2];
    const float* W      = (const float*)d_in[3];
    float* out = (float*)d_out;

    char* ws = (char*)d_ws;
    signed char*    h8        = (signed char*)(ws);                    //  8 MB
    float*          part_m    = (float*)(ws + (16u << 20));            //  4 MB
    float*          part_s    = (float*)(ws + (24u << 20));            //  4 MB
    float*          lab_logit = (float*)(ws + (32u << 20));            // 16 KB
    float*          wnll      = (float*)(ws + (32u << 20) + 16384);    // 16 KB
    signed char*    wseg      = (signed char*)(ws + (32u << 20) + 32768);
    const size_t base = (size_t)(32u << 20) + 32768;

    long segmax = 0;
    if (ws_size > base) segmax = (long)((ws_size - base) / (size_t)DIM);
    segmax &= ~255L;
    if (segmax > VOCAB) segmax = VOCAB;
    if (segmax < 256)   segmax = 256;   // require ws_size >= ~33.5 MB

    // 0) h -> i8 (x16)
    convert_f32_i8<<<(N_TOK * DIM) / (256 * 8), 256, 0, stream>>>(
        h, h8, (long)N_TOK * DIM, 16.0f);

    // 1) segmented W -> i8 (x1024) + fused GEMM/LSE partials
    for (long v0 = 0; v0 < VOCAB; v0 += segmax) {
        const long rows = (VOCAB - v0) < segmax ? (VOCAB - v0) : segmax;
        convert_f32_i8<<<(int)(rows * DIM / (256 * 8)), 256, 0, stream>>>(
            W + v0 * DIM, wseg, rows * (long)DIM, 1024.0f);
        const int nwg = (int)(rows / BN) * NTB;
        gemm_lse<<<nwg, 512, 0, stream>>>(h8, wseg, part_m, part_s,
                                          (int)(v0 / BN));
    }

    // 2) exact label logits (fp32)
    label_dot<<<N_TOK, 256, 0, stream>>>(h, W, labels, lab_logit);

    // 3) per-token LSE merge -> w*nll
    finalize_nll<<<N_TOK / 4, 256, 0, stream>>>(part_m, part_s, lab_logit,
                                                wts, wnll);

    // 4) weighted mean
    final_reduce<<<1, 1024, 0, stream>>>(wnll, wts, out);
}

// Round 21
// 765.742 us; speedup vs baseline: 1.3490x; 1.3490x over previous
//
#include <hip/hip_runtime.h>

// ---------------------------------------------------------------------------
// FusedSparseLMHead: weighted-mean CE over h @ W^T without materializing logits.
//   h: [4096, 2048] f32, W: [65536, 2048] f32, labels: [4096] int, w: [4096] f32
// Round 21: RESTORE r15 verbatim -- the measured optimum (765 us total).
//   i8 GEMM via mfma_i32_16x16x64_i8 (i32x4 operand = one ds_read_b128, zero
//   repack, exact i32 accum). 256^2 tile, BK=128, 2-phase/3-barrier K-tile,
//   A(t+1) staged ph0 / B(t+2) staged ph1, boundary vmcnt(4) counted.
//   Subsequent rounds r16-r20 tested occupancy/tile/barrier/instruction-shape
//   variants -- ALL measured worse; this structure is the plateau optimum.
//   Quantization: h*16 rne clamp127 (step 1/16), W*1024 (step ~0.001);
//   epilogue /16384 exact; label logit exact fp32.
// ---------------------------------------------------------------------------

typedef __attribute__((ext_vector_type(4)))  float f32x4;
typedef __attribute__((ext_vector_type(8)))  float f32x8;
typedef __attribute__((ext_vector_type(4)))  int   i32x4;

#define N_TOK 4096
#define DIM   2048          // i8 bytes per row
#define VOCAB 65536
#define BM    256
#define BN    256
#define BK    128           // i8 elements per K-tile
#define NT    (DIM / BK)    // 16 K-tiles
#define NCH   (VOCAB / BN)  // 256 vocab chunks
#define NTB   (N_TOK / BM)  // 16 token blocks

__device__ __forceinline__ void gload_lds16(const void* g, void* l) {
    __builtin_amdgcn_global_load_lds(
        (const __attribute__((address_space(1))) void*)g,
        (__attribute__((address_space(3))) void*)l, 16, 0, 0);
}

__device__ __forceinline__ void bar() {
    asm volatile("" ::: "memory");
    __builtin_amdgcn_s_barrier();
    asm volatile("" ::: "memory");
}

// ------------------------------------------------- convert f32 -> int8 -----
__global__ __launch_bounds__(256) void convert_f32_i8(
    const float* __restrict__ src, signed char* __restrict__ dst,
    long n, float scale)
{
    long i = ((long)blockIdx.x * 256 + threadIdx.x) * 8;
    if (i + 8 > n) return;
    f32x8 v = *(const f32x8*)(src + i);
    signed char o[8];
    #pragma unroll
    for (int j = 0; j < 8; ++j) {
        float x = v[j] * scale;
        x = fminf(fmaxf(x, -127.0f), 127.0f);
        o[j] = (signed char)__float2int_rn(x);
    }
    *(uint2*)(dst + i) = *(const uint2*)o;   // plain contiguous, coalesced
}

// ------------------- i8 16x16x64 2-phase/3-barrier 256^2 GEMM+LSE ----------
__global__ __launch_bounds__(512, 2) void gemm_lse(
    const signed char* __restrict__ h8,      // [4096][2048] i8 (x16)
    const signed char* __restrict__ W8,      // [seg_rows][2048] i8 (x1024)
    float* __restrict__ part_m, float* __restrict__ part_s, int chunk0)
{
    __shared__ unsigned char A_lds[2][32768];   // [par][256r x 128B] 64 KB
    __shared__ unsigned char B_lds[2][32768];   // 64 KB

    const int tid  = threadIdx.x;
    const int lane = tid & 63;
    const int w    = tid >> 6;       // wave 0..7
    const int wm   = w >> 2;         // 0..1 : token half (128 rows)
    const int wn   = w & 3;          // 0..3 : vocab quarter (64 cols)

    // bijective XCD-aware remap, token-fastest decode
    const int nwg  = gridDim.x;
    const int orig = blockIdx.x;
    const int q8 = nwg >> 3, r8 = nwg & 7;
    const int xcd = orig & 7;
    const int wg  = (xcd < r8 ? xcd * (q8 + 1) : r8 * (q8 + 1) + (xcd - r8) * q8)
                    + (orig >> 3);
    const int tok_blk = wg & (NTB - 1);
    const int voc_blk = wg >> 4;                 // NTB == 16

    const long arow0 = (long)tok_blk * BM;
    const signed char* Ab = h8 + arow0 * DIM;
    const signed char* Bb = W8 + (long)voc_blk * BN * DIM;

    i32x4 acc[8][4];
    #pragma unroll
    for (int i = 0; i < 8; ++i)
        #pragma unroll
        for (int j = 0; j < 4; ++j)
            acc[i][j] = (i32x4){0, 0, 0, 0};

    // ---- staging: tile = 256r x 8 chunks(16B); 4 sweeps x 1 gload each.
    // Sweep j rows [j*64, j*64+64): r = j*64 + (tid>>3), c = tid&7;
    // src chunk c^(r&7) -> LDS[r][c] = G[r][c^(r&7)] (linear dest).
    const long soff = (long)(tid >> 3) * DIM + ((tid & 7) ^ ((tid >> 3) & 7)) * 16;
    const int  sdb  = w * 1024;     // wave-uniform dest base (bytes)

#define SW_A(t, j, PD)                                                        \
    gload_lds16(Ab + (t) * BK + soff + (long)(j) * 64 * DIM,                  \
                (char*)&A_lds[PD][0] + sdb + (j) * 8192);
#define SW_B(t, j, PD)                                                        \
    gload_lds16(Bb + (t) * BK + soff + (long)(j) * 64 * DIM,                  \
                (char*)&B_lds[PD][0] + sdb + (j) * 8192);

    // ---- fragment reads: row = base+lrow; k-group g slice = 16 contiguous
    // bytes at chunk (lane>>4) + 4g, stored at chunk ^ (lane&7). One b128 =
    // one MFMA operand.
    const int lrow = lane & 15;
    const int cxe0 = (((lane >> 4) + 0) ^ (lane & 7)) * 16;   // k-group 0
    const int cxe1 = (((lane >> 4) + 4) ^ (lane & 7)) * 16;   // k-group 1

#define LDF2(D, BASE, ROWB)                                                   \
    D[0] = *(const i32x4*)((BASE) + (ROWB) + cxe0);                           \
    D[1] = *(const i32x4*)((BASE) + (ROWB) + cxe1);

    // 32 MFMA per phase: 2 k-groups x 4 m x 4 nf over acc[MB..MB+3].
#define MFMA32(MB, AR)                                                        \
    __builtin_amdgcn_s_setprio(1);                                            \
    _Pragma("unroll")                                                         \
    for (int g = 0; g < 2; ++g)                                               \
        _Pragma("unroll")                                                     \
        for (int m = 0; m < 4; ++m)                                           \
            _Pragma("unroll")                                                 \
            for (int nf = 0; nf < 4; ++nf)                                    \
                acc[(MB) + m][nf] = __builtin_amdgcn_mfma_i32_16x16x64_i8(    \
                    AR[m][g], bR[nf][g], acc[(MB) + m][nf], 0, 0, 0);         \
    __builtin_amdgcn_s_setprio(0);

#define WAITL()                                                               \
    asm volatile("s_waitcnt lgkmcnt(0)" ::: "memory");                        \
    __builtin_amdgcn_sched_barrier(0);

// One K-tile(128): 2 phases, 3 barriers.
#define KTILE(P, t)                                                           \
    {                                                                         \
        const char* Ah = (const char*)&A_lds[P][0] + wm * 16384;              \
        const char* Bh = (const char*)&B_lds[P][0] + wn * 8192;               \
        i32x4 bR[4][2], aR[4][2];                                             \
        /* ph0: LDB(8) + LDA mf0-3(8) | stage A(t+1) sweeps 0-3 */            \
        LDF2(bR[0], Bh, 0 * 2048 + lrow * 128)                                \
        LDF2(bR[1], Bh, 1 * 2048 + lrow * 128)                                \
        LDF2(bR[2], Bh, 2 * 2048 + lrow * 128)                                \
        LDF2(bR[3], Bh, 3 * 2048 + lrow * 128)                                \
        LDF2(aR[0], Ah, 0 * 2048 + lrow * 128)                                \
        LDF2(aR[1], Ah, 1 * 2048 + lrow * 128)                                \
        LDF2(aR[2], Ah, 2 * 2048 + lrow * 128)                                \
        LDF2(aR[3], Ah, 3 * 2048 + lrow * 128)                                \
        if ((t) + 1 < NT) {                                                   \
            SW_A((t) + 1, 0, (P) ^ 1) SW_A((t) + 1, 1, (P) ^ 1)               \
            SW_A((t) + 1, 2, (P) ^ 1) SW_A((t) + 1, 3, (P) ^ 1)               \
        }                                                                     \
        bar(); WAITL()                                                        \
        MFMA32(0, aR)                                                         \
        /* ph1: LDA mf4-7(8) | bar2 | stage B(t+2) | lgkm0 | 32 MFMA */       \
        LDF2(aR[0], Ah, 4 * 2048 + lrow * 128)                                \
        LDF2(aR[1], Ah, 5 * 2048 + lrow * 128)                                \
        LDF2(aR[2], Ah, 6 * 2048 + lrow * 128)                                \
        LDF2(aR[3], Ah, 7 * 2048 + lrow * 128)                                \
        bar();                                                                \
        if ((t) + 2 < NT) {                                                   \
            SW_B((t) + 2, 0, P) SW_B((t) + 2, 1, P)                           \
            SW_B((t) + 2, 2, P) SW_B((t) + 2, 3, P)                           \
        }                                                                     \
        WAITL()                                                               \
        MFMA32(4, aR)                                                         \
        if ((t) < NT - 2) { asm volatile("s_waitcnt vmcnt(4)" ::: "memory"); }\
        else              { asm volatile("s_waitcnt vmcnt(0)" ::: "memory"); }\
        bar();                                                                \
    }

    // prologue: A(0)->A[0], B(0)->B[0], B(1)->B[1]; vmcnt(4): A(0),B(0)
    // landed, B(1) floats (drained by boundary(0)'s vmcnt(4) before t=1).
    SW_A(0, 0, 0) SW_A(0, 1, 0) SW_A(0, 2, 0) SW_A(0, 3, 0)
    SW_B(0, 0, 0) SW_B(0, 1, 0) SW_B(0, 2, 0) SW_B(0, 3, 0)
    SW_B(1, 0, 1) SW_B(1, 1, 1) SW_B(1, 2, 1) SW_B(1, 3, 1)
    asm volatile("s_waitcnt vmcnt(4)" ::: "memory");
    bar();

    for (int t = 0; t < NT; t += 2) {
        KTILE(0, t)
        KTILE(1, t + 1)
    }
#undef KTILE
#undef SW_A
#undef SW_B
#undef LDF2
#undef MFMA32
#undef WAITL

    // ---- epilogue: exact dequant (1/16384), per-token (max, sumexp) -------
    // C frag (verified): row = wm*128 + mf*16 + (lane>>4)*4 + r;
    // col = wn*64 + nf*16 + (lane&15). 16-wide shfl only.
    const float INV = 1.0f / 16384.0f;
    float* red_m = (float*)&A_lds[0][0];          // 4 KB
    float* red_s = ((float*)&A_lds[0][0]) + 1024; // 4 KB
    #pragma unroll
    for (int mf = 0; mf < 8; ++mf) {
        #pragma unroll
        for (int r = 0; r < 4; ++r) {
            float v0 = (float)acc[mf][0][r] * INV;
            float v1 = (float)acc[mf][1][r] * INV;
            float v2 = (float)acc[mf][2][r] * INV;
            float v3 = (float)acc[mf][3][r] * INV;
            float mx = fmaxf(fmaxf(v0, v1), fmaxf(v2, v3));
            #pragma unroll
            for (int msk = 1; msk < 16; msk <<= 1)
                mx = fmaxf(mx, __shfl_xor(mx, msk, 64));
            float se = __expf(v0 - mx) + __expf(v1 - mx) +
                       __expf(v2 - mx) + __expf(v3 - mx);
            #pragma unroll
            for (int msk = 1; msk < 16; msk <<= 1)
                se += __shfl_xor(se, msk, 64);
            if ((lane & 15) == 0) {
                const int row = wm * 128 + mf * 16 + (lane >> 4) * 4 + r;
                red_m[row * 4 + wn] = mx;
                red_s[row * 4 + wn] = se;
            }
        }
    }
    __syncthreads();
    if (tid < 256) {
        float M = red_m[tid * 4], S = red_s[tid * 4];
        #pragma unroll
        for (int j = 1; j < 4; ++j) {
            const float m2 = red_m[tid * 4 + j], s2 = red_s[tid * 4 + j];
            const float Mn = fmaxf(M, m2);
            S = S * __expf(M - Mn) + s2 * __expf(m2 - Mn);
            M = Mn;
        }
        part_m[(arow0 + tid) * NCH + chunk0 + voc_blk] = M;
        part_s[(arow0 + tid) * NCH + chunk0 + voc_blk] = S;
    }
}

// ------------------------------------------------------- exact label dot ----
__global__ __launch_bounds__(256) void label_dot(
    const float* __restrict__ h, const float* __restrict__ W,
    const void* __restrict__ labels, float* __restrict__ lab_logit)
{
    bool is64 = true;
    #pragma unroll
    for (int i = 0; i < 8; ++i) {
        long long v = ((const long long*)labels)[i];
        if (v < 0 || v >= VOCAB) is64 = false;
    }
    const int t = blockIdx.x;
    const int lab = is64 ? (int)((const long long*)labels)[t]
                         : ((const int*)labels)[t];
    const float4* hp = (const float4*)(h + (long)t * DIM);
    const float4* wp = (const float4*)(W + (long)lab * DIM);
    float s = 0.f;
    #pragma unroll
    for (int j = 0; j < 2; ++j) {
        const float4 a = hp[threadIdx.x + j * 256];
        const float4 b = wp[threadIdx.x + j * 256];
        s += a.x * b.x + a.y * b.y + a.z * b.z + a.w * b.w;
    }
    #pragma unroll
    for (int msk = 1; msk < 64; msk <<= 1) s += __shfl_xor(s, msk, 64);
    __shared__ float ps[4];
    if ((threadIdx.x & 63) == 0) ps[threadIdx.x >> 6] = s;
    __syncthreads();
    if (threadIdx.x == 0) lab_logit[t] = ps[0] + ps[1] + ps[2] + ps[3];
}

// ---------------------------------------------------- per-token LSE merge ---
__global__ __launch_bounds__(256) void finalize_nll(
    const float* __restrict__ part_m, const float* __restrict__ part_s,
    const float* __restrict__ lab_logit, const float* __restrict__ wts,
    float* __restrict__ wnll)
{
    const int t    = blockIdx.x * 4 + (threadIdx.x >> 6);  // one wave / token
    const int lane = threadIdx.x & 63;
    float m = -3.4e38f, s = 0.f;
    #pragma unroll
    for (int j = 0; j < 4; ++j) {
        const int c = j * 64 + lane;
        const float pm = part_m[(long)t * NCH + c];
        const float ps = part_s[(long)t * NCH + c];
        const float M = fmaxf(m, pm);
        s = s * __expf(m - M) + ps * __expf(pm - M);
        m = M;
    }
    #pragma unroll
    for (int msk = 1; msk < 64; msk <<= 1) {
        const float om = __shfl_xor(m, msk, 64);
        const float os = __shfl_xor(s, msk, 64);
        const float M = fmaxf(m, om);
        s = s * __expf(m - M) + os * __expf(om - M);
        m = M;
    }
    if (lane == 0) {
        const float lse = m + logf(s);
        wnll[t] = wts[t] * (lse - lab_logit[t]);
    }
}

// -------------------------------------------------- deterministic reduce ----
__global__ __launch_bounds__(1024) void final_reduce(
    const float* __restrict__ wnll, const float* __restrict__ wts,
    float* __restrict__ out)
{
    float a = 0.f, b = 0.f;
    #pragma unroll
    for (int j = 0; j < 4; ++j) {
        const int i = threadIdx.x + j * 1024;
        a += wnll[i];
        b += wts[i];
    }
    #pragma unroll
    for (int msk = 1; msk < 64; msk <<= 1) {
        a += __shfl_xor(a, msk, 64);
        b += __shfl_xor(b, msk, 64);
    }
    __shared__ float pa[16], pb[16];
    if ((threadIdx.x & 63) == 0) {
        pa[threadIdx.x >> 6] = a;
        pb[threadIdx.x >> 6] = b;
    }
    __syncthreads();
    if (threadIdx.x == 0) {
        float A = 0.f, B = 0.f;
        #pragma unroll
        for (int i = 0; i < 16; ++i) { A += pa[i]; B += pb[i]; }
        out[0] = A / B;
    }
}

// ----------------------------------------------------------------- launch ---
extern "C" void kernel_launch(void* const* d_in, const int* in_sizes, int n_in,
                              void* d_out, int out_size, void* d_ws, size_t ws_size,
                              hipStream_t stream)
{
    const float* h      = (const float*)d_in[0];
    const void*  labels = d_in[1];
    const float* wts    = (const float*)d_in[2];
    const float* W      = (const float*)d_in[3];
    float* out = (float*)d_out;

    char* ws = (char*)d_ws;
    signed char*    h8        = (signed char*)(ws);                    //  8 MB
    float*          part_m    = (float*)(ws + (16u << 20));            //  4 MB
    float*          part_s    = (float*)(ws + (24u << 20));            //  4 MB
    float*          lab_logit = (float*)(ws + (32u << 20));            // 16 KB
    float*          wnll      = (float*)(ws + (32u << 20) + 16384);    // 16 KB
    signed char*    wseg      = (signed char*)(ws + (32u << 20) + 32768);
    const size_t base = (size_t)(32u << 20) + 32768;

    long segmax = 0;
    if (ws_size > base) segmax = (long)((ws_size - base) / (size_t)DIM);
    segmax &= ~255L;
    if (segmax > VOCAB) segmax = VOCAB;
    if (segmax < 256)   segmax = 256;   // require ws_size >= ~33.5 MB

    // 0) h -> i8 (x16)
    convert_f32_i8<<<(N_TOK * DIM) / (256 * 8), 256, 0, stream>>>(
        h, h8, (long)N_TOK * DIM, 16.0f);

    // 1) segmented W -> i8 (x1024) + fused GEMM/LSE partials
    for (long v0 = 0; v0 < VOCAB; v0 += segmax) {
        const long rows = (VOCAB - v0) < segmax ? (VOCAB - v0) : segmax;
        convert_f32_i8<<<(int)(rows * DIM / (256 * 8)), 256, 0, stream>>>(
            W + v0 * DIM, wseg, rows * (long)DIM, 1024.0f);
        const int nwg = (int)(rows / BN) * NTB;
        gemm_lse<<<nwg, 512, 0, stream>>>(h8, wseg, part_m, part_s,
                                          (int)(v0 / BN));
    }

    // 2) exact label logits (fp32)
    label_dot<<<N_TOK, 256, 0, stream>>>(h, W, labels, lab_logit);

    // 3) per-token LSE merge -> w*nll
    finalize_nll<<<N_TOK / 4, 256, 0, stream>>>(part_m, part_s, lab_logit,
                                                wts, wnll);

    // 4) weighted mean
    final_reduce<<<1, 1024, 0, stream>>>(wnll, wts, out);
}